// Round 1
// baseline (582.351 us; speedup 1.0000x reference)
//
#include <hip/hip_runtime.h>
#include <math.h>

#define NN 100000
#define NE 640000
#define DD 128
#define NBLK 391   // ceil(NN/256)

// ---------------- workspace layout (bytes, 512-aligned) ----------------
// deg    int[NN]        @ 0
// dinv   float[NN]      @ 400384
// off    int[NN+1]      @ 800768
// cursor int[NN]        @ 1201152
// bsum   int[NBLK]      @ 1601536
// bbase  int[NBLK]      @ 1603584
// epack  int2[NE]       @ 1605632
// H      float[NN*DD]   @ 6725632
// total ~57.9 MB
static const size_t OFF_DEG    = 0;
static const size_t OFF_DINV   = 400384;
static const size_t OFF_OFF    = 800768;
static const size_t OFF_CURSOR = 1201152;
static const size_t OFF_BSUM   = 1601536;
static const size_t OFF_BBASE  = 1603584;
static const size_t OFF_EPACK  = 1605632;
static const size_t OFF_H      = 6725632;

// ---------------- CSR build ----------------

__global__ __launch_bounds__(256) void count_deg(const int* __restrict__ coli,
                                                 int* __restrict__ deg) {
    int e = blockIdx.x * 256 + threadIdx.x;
    if (e < NE) atomicAdd(&deg[coli[e]], 1);
}

__global__ __launch_bounds__(256) void compute_dinv(const int* __restrict__ deg,
                                                    float* __restrict__ dinv) {
    int n = blockIdx.x * 256 + threadIdx.x;
    if (n < NN) {
        int d = deg[n];
        dinv[n] = (d > 0) ? 1.0f / sqrtf((float)d) : 0.0f;
    }
}

// phase 1: per-block exclusive scan (local), block totals to bsum
__global__ __launch_bounds__(256) void scan_blocks(const int* __restrict__ deg,
                                                   int* __restrict__ loff,
                                                   int* __restrict__ bsum) {
    int tid = threadIdx.x;
    int i = blockIdx.x * 256 + tid;
    int v = (i < NN) ? deg[i] : 0;
    int lane = tid & 63, wid = tid >> 6;
    int sv = v;
    #pragma unroll
    for (int s = 1; s < 64; s <<= 1) {
        int t = __shfl_up(sv, s, 64);
        if (lane >= s) sv += t;
    }
    __shared__ int wtot[4];
    if (lane == 63) wtot[wid] = sv;
    __syncthreads();
    if (tid == 0) {
        int r = 0;
        #pragma unroll
        for (int w = 0; w < 4; ++w) { int t = wtot[w]; wtot[w] = r; r += t; }
    }
    __syncthreads();
    int incl = sv + wtot[wid];
    if (i < NN) loff[i] = incl - v;           // block-local exclusive
    if (tid == 255) bsum[blockIdx.x] = incl;  // block total
}

// phase 2: single-block scan of NBLK block totals -> per-block bases + off[NN]
__global__ __launch_bounds__(512) void scan_partials(const int* __restrict__ bsum,
                                                     int* __restrict__ bbase,
                                                     int* __restrict__ off) {
    int tid = threadIdx.x;
    int v = (tid < NBLK) ? bsum[tid] : 0;
    int lane = tid & 63, wid = tid >> 6;
    int sv = v;
    #pragma unroll
    for (int s = 1; s < 64; s <<= 1) {
        int t = __shfl_up(sv, s, 64);
        if (lane >= s) sv += t;
    }
    __shared__ int wtot[8];
    if (lane == 63) wtot[wid] = sv;
    __syncthreads();
    if (tid == 0) {
        int r = 0;
        #pragma unroll
        for (int w = 0; w < 8; ++w) { int t = wtot[w]; wtot[w] = r; r += t; }
    }
    __syncthreads();
    int incl = sv + wtot[wid];
    if (tid < NBLK) bbase[tid] = incl - v;
    if (tid == NBLK - 1) off[NN] = incl;      // grand total (= NE)
}

// phase 3: add block base, materialize cursor copy
__global__ __launch_bounds__(256) void add_base(int* __restrict__ off,
                                                int* __restrict__ cursor,
                                                const int* __restrict__ bbase) {
    int i = blockIdx.x * 256 + threadIdx.x;
    if (i < NN) {
        int v = off[i] + bbase[blockIdx.x];
        off[i] = v;
        cursor[i] = v;
    }
}

// bucket fill: epack[pos] = {src, norm}
__global__ __launch_bounds__(256) void fill_csr(const int* __restrict__ rowi,
                                                const int* __restrict__ coli,
                                                const float* __restrict__ dinv,
                                                int* __restrict__ cursor,
                                                int2* __restrict__ epack) {
    int e = blockIdx.x * 256 + threadIdx.x;
    if (e < NE) {
        int s = rowi[e], d = coli[e];
        int pos = atomicAdd(&cursor[d], 1);
        float w = dinv[s] * dinv[d];
        epack[pos] = make_int2(s, __float_as_int(w));
    }
}

// ---------------- per-layer kernels ----------------

// H[r, :] = X[r, :] @ W   (X: NNxDD, W: DDxDD row-major)
// block: 256 threads, tile 64 rows x 128 cols; thread: 8 rows x 4 cols
__global__ __launch_bounds__(256) void gemm128(const float* __restrict__ X,
                                               const float* __restrict__ W,
                                               float* __restrict__ H) {
    int tx = threadIdx.x & 31;     // col group
    int ty = threadIdx.x >> 5;     // row group 0..7
    int row0 = blockIdx.x * 64 + ty * 8;
    int c0 = tx * 4;

    const float* xrow[8];
    #pragma unroll
    for (int r = 0; r < 8; ++r) {
        int row = row0 + r;
        if (row >= NN) row = NN - 1;   // clamp loads; stores guarded
        xrow[r] = X + (size_t)row * DD;
    }

    float acc[8][4];
    #pragma unroll
    for (int r = 0; r < 8; ++r)
        #pragma unroll
        for (int c = 0; c < 4; ++c) acc[r][c] = 0.0f;

    for (int k = 0; k < DD; k += 4) {
        float4 w0 = *(const float4*)(W + (size_t)(k + 0) * DD + c0);
        float4 w1 = *(const float4*)(W + (size_t)(k + 1) * DD + c0);
        float4 w2 = *(const float4*)(W + (size_t)(k + 2) * DD + c0);
        float4 w3 = *(const float4*)(W + (size_t)(k + 3) * DD + c0);
        #pragma unroll
        for (int r = 0; r < 8; ++r) {
            float4 xv = *(const float4*)(xrow[r] + k);
            acc[r][0] += xv.x * w0.x + xv.y * w1.x + xv.z * w2.x + xv.w * w3.x;
            acc[r][1] += xv.x * w0.y + xv.y * w1.y + xv.z * w2.y + xv.w * w3.y;
            acc[r][2] += xv.x * w0.z + xv.y * w1.z + xv.z * w2.z + xv.w * w3.z;
            acc[r][3] += xv.x * w0.w + xv.y * w1.w + xv.z * w2.w + xv.w * w3.w;
        }
    }

    #pragma unroll
    for (int r = 0; r < 8; ++r) {
        int row = row0 + r;
        if (row < NN) {
            *(float4*)(H + (size_t)row * DD + c0) =
                make_float4(acc[r][0], acc[r][1], acc[r][2], acc[r][3]);
        }
    }
}

// Y[n, :] = sum_{j in CSR bucket n} w_j * H[src_j, :] + bias ; optional ReLU
// 32 lanes per node (float4 each), 8 nodes per 256-thread block
__global__ __launch_bounds__(256) void aggregate(const float* __restrict__ H,
                                                 const int* __restrict__ off,
                                                 const int2* __restrict__ epack,
                                                 const float* __restrict__ bias,
                                                 float* __restrict__ Y,
                                                 int do_relu) {
    int node = blockIdx.x * 8 + (threadIdx.x >> 5);
    int lane = threadIdx.x & 31;
    int c0 = lane * 4;

    int s = off[node];
    int e = off[node + 1];

    float4 acc = make_float4(0.f, 0.f, 0.f, 0.f);
    for (int j = s; j < e; ++j) {
        int2 p = epack[j];
        float w = __int_as_float(p.y);
        float4 hv = *(const float4*)(H + (size_t)p.x * DD + c0);
        acc.x += hv.x * w;
        acc.y += hv.y * w;
        acc.z += hv.z * w;
        acc.w += hv.w * w;
    }

    float4 bv = *(const float4*)(bias + c0);
    acc.x += bv.x; acc.y += bv.y; acc.z += bv.z; acc.w += bv.w;
    if (do_relu) {
        acc.x = fmaxf(acc.x, 0.f);
        acc.y = fmaxf(acc.y, 0.f);
        acc.z = fmaxf(acc.z, 0.f);
        acc.w = fmaxf(acc.w, 0.f);
    }
    *(float4*)(Y + (size_t)node * DD + c0) = acc;
}

// ---------------- launch ----------------

extern "C" void kernel_launch(void* const* d_in, const int* in_sizes, int n_in,
                              void* d_out, int out_size, void* d_ws, size_t ws_size,
                              hipStream_t stream) {
    const float* x  = (const float*)d_in[0];
    const int*   ei = (const int*)d_in[1];   // [2, NE] flattened, int32
    const float* W  = (const float*)d_in[3]; // [3, DD, DD]
    const float* b  = (const float*)d_in[4]; // [3, DD]
    float* out = (float*)d_out;

    char* ws = (char*)d_ws;
    int*   deg    = (int*)(ws + OFF_DEG);
    float* dinv   = (float*)(ws + OFF_DINV);
    int*   off    = (int*)(ws + OFF_OFF);
    int*   cursor = (int*)(ws + OFF_CURSOR);
    int*   bsum   = (int*)(ws + OFF_BSUM);
    int*   bbase  = (int*)(ws + OFF_BBASE);
    int2*  epack  = (int2*)(ws + OFF_EPACK);
    float* H      = (float*)(ws + OFF_H);

    const int* rowi = ei;        // sources
    const int* coli = ei + NE;   // targets

    // --- CSR build (once per call) ---
    hipMemsetAsync(deg, 0, NN * sizeof(int), stream);
    count_deg<<<(NE + 255) / 256, 256, 0, stream>>>(coli, deg);
    compute_dinv<<<(NN + 255) / 256, 256, 0, stream>>>(deg, dinv);
    scan_blocks<<<NBLK, 256, 0, stream>>>(deg, off, bsum);
    scan_partials<<<1, 512, 0, stream>>>(bsum, bbase, off);
    add_base<<<NBLK, 256, 0, stream>>>(off, cursor, bbase);
    fill_csr<<<(NE + 255) / 256, 256, 0, stream>>>(rowi, coli, dinv, cursor, epack);

    // --- 3 GCN layers; x1->out, x2->out, x3->out (GEMM consumes out first) ---
    for (int l = 0; l < 3; ++l) {
        const float* xin = (l == 0) ? x : out;
        gemm128<<<(NN + 63) / 64, 256, 0, stream>>>(xin, W + (size_t)l * DD * DD, H);
        aggregate<<<NN / 8, 256, 0, stream>>>(H, off, epack, b + (size_t)l * DD, out,
                                              (l < 2) ? 1 : 0);
    }
}

// Round 2
// 564.939 us; speedup vs baseline: 1.0308x; 1.0308x over previous
//
#include <hip/hip_runtime.h>
#include <math.h>

#define NN 100000
#define NE 640000
#define DD 128
#define NBLK 391   // ceil(NN/256)

// ---------------- workspace layout (bytes, 512-aligned) ----------------
static const size_t OFF_DEG    = 0;
static const size_t OFF_DINV   = 400384;
static const size_t OFF_OFF    = 800768;
static const size_t OFF_CURSOR = 1201152;
static const size_t OFF_BSUM   = 1601536;
static const size_t OFF_BBASE  = 1603584;
static const size_t OFF_EIDX   = 1605632;   // int[NE]
static const size_t OFF_H      = 4166144;   // float[NN*DD]

// ---------------- CSR build ----------------

__global__ __launch_bounds__(256) void count_deg(const int* __restrict__ coli,
                                                 int* __restrict__ deg) {
    int e = blockIdx.x * 256 + threadIdx.x;
    if (e < NE) atomicAdd(&deg[coli[e]], 1);
}

__global__ __launch_bounds__(256) void compute_dinv(const int* __restrict__ deg,
                                                    float* __restrict__ dinv) {
    int n = blockIdx.x * 256 + threadIdx.x;
    if (n < NN) {
        int d = deg[n];
        dinv[n] = (d > 0) ? 1.0f / sqrtf((float)d) : 0.0f;
    }
}

// phase 1: per-block exclusive scan (local), block totals to bsum
__global__ __launch_bounds__(256) void scan_blocks(const int* __restrict__ deg,
                                                   int* __restrict__ loff,
                                                   int* __restrict__ bsum) {
    int tid = threadIdx.x;
    int i = blockIdx.x * 256 + tid;
    int v = (i < NN) ? deg[i] : 0;
    int lane = tid & 63, wid = tid >> 6;
    int sv = v;
    #pragma unroll
    for (int s = 1; s < 64; s <<= 1) {
        int t = __shfl_up(sv, s, 64);
        if (lane >= s) sv += t;
    }
    __shared__ int wtot[4];
    if (lane == 63) wtot[wid] = sv;
    __syncthreads();
    if (tid == 0) {
        int r = 0;
        #pragma unroll
        for (int w = 0; w < 4; ++w) { int t = wtot[w]; wtot[w] = r; r += t; }
    }
    __syncthreads();
    int incl = sv + wtot[wid];
    if (i < NN) loff[i] = incl - v;
    if (tid == 255) bsum[blockIdx.x] = incl;
}

// phase 2: single-block scan of NBLK block totals
__global__ __launch_bounds__(512) void scan_partials(const int* __restrict__ bsum,
                                                     int* __restrict__ bbase,
                                                     int* __restrict__ off) {
    int tid = threadIdx.x;
    int v = (tid < NBLK) ? bsum[tid] : 0;
    int lane = tid & 63, wid = tid >> 6;
    int sv = v;
    #pragma unroll
    for (int s = 1; s < 64; s <<= 1) {
        int t = __shfl_up(sv, s, 64);
        if (lane >= s) sv += t;
    }
    __shared__ int wtot[8];
    if (lane == 63) wtot[wid] = sv;
    __syncthreads();
    if (tid == 0) {
        int r = 0;
        #pragma unroll
        for (int w = 0; w < 8; ++w) { int t = wtot[w]; wtot[w] = r; r += t; }
    }
    __syncthreads();
    int incl = sv + wtot[wid];
    if (tid < NBLK) bbase[tid] = incl - v;
    if (tid == NBLK - 1) off[NN] = incl;
}

// phase 3: add block base, materialize cursor copy
__global__ __launch_bounds__(256) void add_base(int* __restrict__ off,
                                                int* __restrict__ cursor,
                                                const int* __restrict__ bbase) {
    int i = blockIdx.x * 256 + threadIdx.x;
    if (i < NN) {
        int v = off[i] + bbase[blockIdx.x];
        off[i] = v;
        cursor[i] = v;
    }
}

// bucket fill: eidx[pos] = src  (per-edge weight factored out algebraically)
__global__ __launch_bounds__(256) void fill_csr(const int* __restrict__ rowi,
                                                const int* __restrict__ coli,
                                                int* __restrict__ cursor,
                                                int* __restrict__ eidx) {
    int e = blockIdx.x * 256 + threadIdx.x;
    if (e < NE) {
        int s = rowi[e], d = coli[e];
        int pos = atomicAdd(&cursor[d], 1);
        eidx[pos] = s;
    }
}

// ---------------- per-layer kernels ----------------

// H[r,:] = dinv[r] * (X[r,:] @ W)   (X: NNxDD, W: DDxDD row-major)
// block: 512 threads, tile 128 rows x 128 cols; thread: 8 rows x 4 cols
// W staged in LDS (64 KB) -> 2 blocks/CU (LDS-limited), target VGPR<=128.
__global__ __launch_bounds__(512) void gemm_lds(const float* __restrict__ X,
                                                const float* __restrict__ W,
                                                const float* __restrict__ dinv,
                                                float* __restrict__ H) {
    __shared__ float Ws[DD * DD];
    {
        const float4* __restrict__ Wv = (const float4*)W;
        float4* Wsv = (float4*)Ws;
        #pragma unroll
        for (int i = 0; i < 8; ++i)   // 4096 float4 / 512 threads
            Wsv[threadIdx.x + i * 512] = Wv[threadIdx.x + i * 512];
    }
    __syncthreads();

    int tx = threadIdx.x & 31;     // col group: c0 = tx*4
    int ty = threadIdx.x >> 5;     // row group 0..15
    int row0 = blockIdx.x * 128 + ty * 8;
    int c0 = tx * 4;

    const float* xrow[8];
    #pragma unroll
    for (int r = 0; r < 8; ++r) {
        int row = row0 + r;
        if (row >= NN) row = NN - 1;   // clamp loads; stores guarded
        xrow[r] = X + (size_t)row * DD;
    }

    float acc[8][4];
    #pragma unroll
    for (int r = 0; r < 8; ++r)
        #pragma unroll
        for (int c = 0; c < 4; ++c) acc[r][c] = 0.0f;

    for (int k = 0; k < DD; k += 8) {
        float4 xa[8], xb[8];
        #pragma unroll
        for (int r = 0; r < 8; ++r) {
            xa[r] = *(const float4*)(xrow[r] + k);
            xb[r] = *(const float4*)(xrow[r] + k + 4);
        }
        #pragma unroll
        for (int kk = 0; kk < 8; ++kk) {
            float4 wv = *(const float4*)(Ws + (k + kk) * DD + c0);
            #pragma unroll
            for (int r = 0; r < 8; ++r) {
                float xs;
                if (kk == 0) xs = xa[r].x;
                else if (kk == 1) xs = xa[r].y;
                else if (kk == 2) xs = xa[r].z;
                else if (kk == 3) xs = xa[r].w;
                else if (kk == 4) xs = xb[r].x;
                else if (kk == 5) xs = xb[r].y;
                else if (kk == 6) xs = xb[r].z;
                else xs = xb[r].w;
                acc[r][0] = fmaf(xs, wv.x, acc[r][0]);
                acc[r][1] = fmaf(xs, wv.y, acc[r][1]);
                acc[r][2] = fmaf(xs, wv.z, acc[r][2]);
                acc[r][3] = fmaf(xs, wv.w, acc[r][3]);
            }
        }
    }

    #pragma unroll
    for (int r = 0; r < 8; ++r) {
        int row = row0 + r;
        if (row < NN) {
            float s = dinv[row];
            *(float4*)(H + (size_t)row * DD + c0) =
                make_float4(acc[r][0] * s, acc[r][1] * s, acc[r][2] * s, acc[r][3] * s);
        }
    }
}

// Y[n,:] = dinv[n] * sum_{j in bucket n} H[src_j,:] + bias ; optional ReLU
// 32 lanes per node (float4 each), 8 nodes per 256-thread block
__global__ __launch_bounds__(256) void aggregate(const float* __restrict__ H,
                                                 const int* __restrict__ off,
                                                 const int* __restrict__ eidx,
                                                 const float* __restrict__ dinv,
                                                 const float* __restrict__ bias,
                                                 float* __restrict__ Y,
                                                 int do_relu) {
    int node = blockIdx.x * 8 + (threadIdx.x >> 5);
    int lane = threadIdx.x & 31;
    int c0 = lane * 4;

    int s = off[node];
    int e = off[node + 1];

    float4 acc = make_float4(0.f, 0.f, 0.f, 0.f);
    for (int j = s; j < e; ++j) {
        int src = eidx[j];
        float4 hv = *(const float4*)(H + (size_t)src * DD + c0);
        acc.x += hv.x;
        acc.y += hv.y;
        acc.z += hv.z;
        acc.w += hv.w;
    }

    float dn = dinv[node];
    float4 bv = *(const float4*)(bias + c0);
    acc.x = acc.x * dn + bv.x;
    acc.y = acc.y * dn + bv.y;
    acc.z = acc.z * dn + bv.z;
    acc.w = acc.w * dn + bv.w;
    if (do_relu) {
        acc.x = fmaxf(acc.x, 0.f);
        acc.y = fmaxf(acc.y, 0.f);
        acc.z = fmaxf(acc.z, 0.f);
        acc.w = fmaxf(acc.w, 0.f);
    }
    *(float4*)(Y + (size_t)node * DD + c0) = acc;
}

// ---------------- launch ----------------

extern "C" void kernel_launch(void* const* d_in, const int* in_sizes, int n_in,
                              void* d_out, int out_size, void* d_ws, size_t ws_size,
                              hipStream_t stream) {
    const float* x  = (const float*)d_in[0];
    const int*   ei = (const int*)d_in[1];   // [2, NE] flattened, int32
    const float* W  = (const float*)d_in[3]; // [3, DD, DD]
    const float* b  = (const float*)d_in[4]; // [3, DD]
    float* out = (float*)d_out;

    char* ws = (char*)d_ws;
    int*   deg    = (int*)(ws + OFF_DEG);
    float* dinv   = (float*)(ws + OFF_DINV);
    int*   off    = (int*)(ws + OFF_OFF);
    int*   cursor = (int*)(ws + OFF_CURSOR);
    int*   bsum   = (int*)(ws + OFF_BSUM);
    int*   bbase  = (int*)(ws + OFF_BBASE);
    int*   eidx   = (int*)(ws + OFF_EIDX);
    float* H      = (float*)(ws + OFF_H);

    const int* rowi = ei;        // sources
    const int* coli = ei + NE;   // targets

    // --- CSR build (once per call) ---
    hipMemsetAsync(deg, 0, NN * sizeof(int), stream);
    count_deg<<<(NE + 255) / 256, 256, 0, stream>>>(coli, deg);
    compute_dinv<<<(NN + 255) / 256, 256, 0, stream>>>(deg, dinv);
    scan_blocks<<<NBLK, 256, 0, stream>>>(deg, off, bsum);
    scan_partials<<<1, 512, 0, stream>>>(bsum, bbase, off);
    add_base<<<NBLK, 256, 0, stream>>>(off, cursor, bbase);
    fill_csr<<<(NE + 255) / 256, 256, 0, stream>>>(rowi, coli, cursor, eidx);

    // --- 3 GCN layers ---
    for (int l = 0; l < 3; ++l) {
        const float* xin = (l == 0) ? x : out;
        gemm_lds<<<(NN + 127) / 128, 512, 0, stream>>>(xin, W + (size_t)l * DD * DD,
                                                       dinv, H);
        aggregate<<<NN / 8, 256, 0, stream>>>(H, off, eidx, dinv, b + (size_t)l * DD,
                                              out, (l < 2) ? 1 : 0);
    }
}

// Round 3
// 425.354 us; speedup vs baseline: 1.3691x; 1.3282x over previous
//
#include <hip/hip_runtime.h>
#include <math.h>

#define NN 100000
#define NE 640000
#define DD 128
#define NBLK 391   // ceil(NN/256)

typedef __attribute__((ext_vector_type(8))) short short8;   // 8 bf16 = 4 VGPRs
typedef __attribute__((ext_vector_type(4))) float floatx4;  // MFMA C/D

// ---------------- workspace layout (bytes, 512-aligned) ----------------
static const size_t OFF_DEG    = 0;        // int[NN]
static const size_t OFF_DINV   = 400384;   // float[NN]
static const size_t OFF_OFF    = 800768;   // int[NN+1]
static const size_t OFF_CURSOR = 1201152;  // int[NN]
static const size_t OFF_BSUM   = 1601536;  // int[NBLK]
static const size_t OFF_BBASE  = 1603584;  // int[NBLK]
static const size_t OFF_WHP    = 1605632;  // ushort[3*2048*8]
static const size_t OFF_WLP    = 1703936;  // ushort[3*2048*8]
static const size_t OFF_EIDX   = 1802240;  // int[NE]
static const size_t OFF_H      = 4362752;  // float[NN*DD]

__device__ __forceinline__ unsigned bf16_rne(float f) {
    unsigned u = __float_as_uint(f);
    return (u + 0x7FFFu + ((u >> 16) & 1u)) >> 16;
}

// ---------------- CSR build ----------------

__global__ __launch_bounds__(256) void count_deg(const int* __restrict__ coli,
                                                 int* __restrict__ deg) {
    int e = blockIdx.x * 256 + threadIdx.x;
    if (e < NE) atomicAdd(&deg[coli[e]], 1);
}

__global__ __launch_bounds__(256) void compute_dinv(const int* __restrict__ deg,
                                                    float* __restrict__ dinv) {
    int n = blockIdx.x * 256 + threadIdx.x;
    if (n < NN) {
        int d = deg[n];
        dinv[n] = (d > 0) ? 1.0f / sqrtf((float)d) : 0.0f;
    }
}

__global__ __launch_bounds__(256) void scan_blocks(const int* __restrict__ deg,
                                                   int* __restrict__ loff,
                                                   int* __restrict__ bsum) {
    int tid = threadIdx.x;
    int i = blockIdx.x * 256 + tid;
    int v = (i < NN) ? deg[i] : 0;
    int lane = tid & 63, wid = tid >> 6;
    int sv = v;
    #pragma unroll
    for (int s = 1; s < 64; s <<= 1) {
        int t = __shfl_up(sv, s, 64);
        if (lane >= s) sv += t;
    }
    __shared__ int wtot[4];
    if (lane == 63) wtot[wid] = sv;
    __syncthreads();
    if (tid == 0) {
        int r = 0;
        #pragma unroll
        for (int w = 0; w < 4; ++w) { int t = wtot[w]; wtot[w] = r; r += t; }
    }
    __syncthreads();
    int incl = sv + wtot[wid];
    if (i < NN) loff[i] = incl - v;
    if (tid == 255) bsum[blockIdx.x] = incl;
}

__global__ __launch_bounds__(512) void scan_partials(const int* __restrict__ bsum,
                                                     int* __restrict__ bbase,
                                                     int* __restrict__ off) {
    int tid = threadIdx.x;
    int v = (tid < NBLK) ? bsum[tid] : 0;
    int lane = tid & 63, wid = tid >> 6;
    int sv = v;
    #pragma unroll
    for (int s = 1; s < 64; s <<= 1) {
        int t = __shfl_up(sv, s, 64);
        if (lane >= s) sv += t;
    }
    __shared__ int wtot[8];
    if (lane == 63) wtot[wid] = sv;
    __syncthreads();
    if (tid == 0) {
        int r = 0;
        #pragma unroll
        for (int w = 0; w < 8; ++w) { int t = wtot[w]; wtot[w] = r; r += t; }
    }
    __syncthreads();
    int incl = sv + wtot[wid];
    if (tid < NBLK) bbase[tid] = incl - v;
    if (tid == NBLK - 1) off[NN] = incl;
}

__global__ __launch_bounds__(256) void add_base(int* __restrict__ off,
                                                int* __restrict__ cursor,
                                                const int* __restrict__ bbase) {
    int i = blockIdx.x * 256 + threadIdx.x;
    if (i < NN) {
        int v = off[i] + bbase[blockIdx.x];
        off[i] = v;
        cursor[i] = v;
    }
}

__global__ __launch_bounds__(256) void fill_csr(const int* __restrict__ rowi,
                                                const int* __restrict__ coli,
                                                int* __restrict__ cursor,
                                                int* __restrict__ eidx) {
    int e = blockIdx.x * 256 + threadIdx.x;
    if (e < NE) {
        int s = rowi[e], d = coli[e];
        int pos = atomicAdd(&cursor[d], 1);
        eidx[pos] = s;
    }
}

// ---------------- W pre-split into MFMA B-fragment order ----------------
// Fragment (kc, nt): lane holds B[k][n], n = nt*16 + (lane&15),
// k = kc*32 + (lane>>4)*8 + j, j=0..7 contiguous -> one 16B load per frag.
// Layout: [layer][kc][nt][lane][8] for hi and lo separately.
__global__ __launch_bounds__(256) void pack_w(const float* __restrict__ W,
                                              ushort* __restrict__ Whp,
                                              ushort* __restrict__ Wlp) {
    int t = blockIdx.x * 256 + threadIdx.x;
    if (t >= 3 * 2048) return;
    int l = t >> 11;
    int r = t & 2047;
    int kc = r >> 9;
    int nt = (r >> 6) & 7;
    int L  = r & 63;
    int n  = nt * 16 + (L & 15);
    int k0 = kc * 32 + (L >> 4) * 8;
    const float* Wl_ = W + (size_t)l * DD * DD;
    size_t base = ((size_t)l * 2048 + r) * 8;
    #pragma unroll
    for (int j = 0; j < 8; ++j) {
        float f = Wl_[(size_t)(k0 + j) * DD + n];
        unsigned hi = bf16_rne(f);
        float fh = __uint_as_float(hi << 16);
        unsigned lo = bf16_rne(f - fh);
        Whp[base + j] = (ushort)hi;
        Wlp[base + j] = (ushort)lo;
    }
}

// ---------------- MFMA GEMM: H[r,:] = dinv[r] * (X[r,:] @ W) ----------------
// 256 threads = 4 waves; each wave: 16 rows x 128 cols.
// Split-bf16: x = xh+xl, W = wh+wl; acc += xh*wh + xh*wl + xl*wh (3 MFMAs).
__global__ __launch_bounds__(256) void gemm_mfma(const float* __restrict__ X,
                                                 const ushort* __restrict__ Whp,
                                                 const ushort* __restrict__ Wlp,
                                                 const float* __restrict__ dinv,
                                                 float* __restrict__ H) {
    int wave = threadIdx.x >> 6;
    int lane = threadIdx.x & 63;
    int m    = lane & 15;
    int quad = lane >> 4;
    int r0   = blockIdx.x * 64 + wave * 16;

    int row  = r0 + m;
    int rowc = (row < NN) ? row : NN - 1;   // clamp loads; stores guarded
    const float* xrow = X + (size_t)rowc * DD;

    floatx4 acc[8];
    #pragma unroll
    for (int nt = 0; nt < 8; ++nt) acc[nt] = (floatx4){0.f, 0.f, 0.f, 0.f};

    #pragma unroll
    for (int kc = 0; kc < 4; ++kc) {
        int k0 = kc * 32 + quad * 8;
        float4 xa = *(const float4*)(xrow + k0);
        float4 xb = *(const float4*)(xrow + k0 + 4);
        float xs[8] = {xa.x, xa.y, xa.z, xa.w, xb.x, xb.y, xb.z, xb.w};
        short8 ah, al;
        #pragma unroll
        for (int j = 0; j < 8; ++j) {
            unsigned hi = bf16_rne(xs[j]);
            float fh = __uint_as_float(hi << 16);
            unsigned lo = bf16_rne(xs[j] - fh);
            ah[j] = (short)hi;
            al[j] = (short)lo;
        }
        #pragma unroll
        for (int nt = 0; nt < 8; ++nt) {
            size_t fidx = (((size_t)(kc * 8 + nt)) * 64 + lane) * 8;
            short8 bh = *(const short8*)(Whp + fidx);
            short8 bl = *(const short8*)(Wlp + fidx);
            acc[nt] = __builtin_amdgcn_mfma_f32_16x16x32_bf16(al, bh, acc[nt], 0, 0, 0);
            acc[nt] = __builtin_amdgcn_mfma_f32_16x16x32_bf16(ah, bl, acc[nt], 0, 0, 0);
            acc[nt] = __builtin_amdgcn_mfma_f32_16x16x32_bf16(ah, bh, acc[nt], 0, 0, 0);
        }
    }

    // C/D: col = nt*16 + m, row = r0 + quad*4 + i   [m89-verified mapping]
    #pragma unroll
    for (int i = 0; i < 4; ++i) {
        int ro = r0 + quad * 4 + i;
        if (ro < NN) {
            float s = dinv[ro];
            float* hp = H + (size_t)ro * DD + m;
            #pragma unroll
            for (int nt = 0; nt < 8; ++nt)
                hp[nt * 16] = acc[nt][i] * s;
        }
    }
}

// ---------------- aggregate ----------------
// Y[n,:] = dinv[n] * sum_{j in bucket n} H[src_j,:] + bias ; optional ReLU
__global__ __launch_bounds__(256) void aggregate(const float* __restrict__ H,
                                                 const int* __restrict__ off,
                                                 const int* __restrict__ eidx,
                                                 const float* __restrict__ dinv,
                                                 const float* __restrict__ bias,
                                                 float* __restrict__ Y,
                                                 int do_relu) {
    int node = blockIdx.x * 8 + (threadIdx.x >> 5);
    int lane = threadIdx.x & 31;
    int c0 = lane * 4;

    int s = off[node];
    int e = off[node + 1];

    float4 acc = make_float4(0.f, 0.f, 0.f, 0.f);
    for (int j = s; j < e; ++j) {
        int src = eidx[j];
        float4 hv = *(const float4*)(H + (size_t)src * DD + c0);
        acc.x += hv.x;
        acc.y += hv.y;
        acc.z += hv.z;
        acc.w += hv.w;
    }

    float dn = dinv[node];
    float4 bv = *(const float4*)(bias + c0);
    acc.x = acc.x * dn + bv.x;
    acc.y = acc.y * dn + bv.y;
    acc.z = acc.z * dn + bv.z;
    acc.w = acc.w * dn + bv.w;
    if (do_relu) {
        acc.x = fmaxf(acc.x, 0.f);
        acc.y = fmaxf(acc.y, 0.f);
        acc.z = fmaxf(acc.z, 0.f);
        acc.w = fmaxf(acc.w, 0.f);
    }
    *(float4*)(Y + (size_t)node * DD + c0) = acc;
}

// ---------------- launch ----------------

extern "C" void kernel_launch(void* const* d_in, const int* in_sizes, int n_in,
                              void* d_out, int out_size, void* d_ws, size_t ws_size,
                              hipStream_t stream) {
    const float* x  = (const float*)d_in[0];
    const int*   ei = (const int*)d_in[1];   // [2, NE] flattened, int32
    const float* W  = (const float*)d_in[3]; // [3, DD, DD]
    const float* b  = (const float*)d_in[4]; // [3, DD]
    float* out = (float*)d_out;

    char* ws = (char*)d_ws;
    int*    deg    = (int*)(ws + OFF_DEG);
    float*  dinv   = (float*)(ws + OFF_DINV);
    int*    off    = (int*)(ws + OFF_OFF);
    int*    cursor = (int*)(ws + OFF_CURSOR);
    int*    bsum   = (int*)(ws + OFF_BSUM);
    int*    bbase  = (int*)(ws + OFF_BBASE);
    ushort* whp    = (ushort*)(ws + OFF_WHP);
    ushort* wlp    = (ushort*)(ws + OFF_WLP);
    int*    eidx   = (int*)(ws + OFF_EIDX);
    float*  H      = (float*)(ws + OFF_H);

    const int* rowi = ei;        // sources
    const int* coli = ei + NE;   // targets

    // --- CSR build + W pre-split (once per call) ---
    hipMemsetAsync(deg, 0, NN * sizeof(int), stream);
    count_deg<<<(NE + 255) / 256, 256, 0, stream>>>(coli, deg);
    compute_dinv<<<(NN + 255) / 256, 256, 0, stream>>>(deg, dinv);
    scan_blocks<<<NBLK, 256, 0, stream>>>(deg, off, bsum);
    scan_partials<<<1, 512, 0, stream>>>(bsum, bbase, off);
    add_base<<<NBLK, 256, 0, stream>>>(off, cursor, bbase);
    fill_csr<<<(NE + 255) / 256, 256, 0, stream>>>(rowi, coli, cursor, eidx);
    pack_w<<<(3 * 2048 + 255) / 256, 256, 0, stream>>>(W, whp, wlp);

    // --- 3 GCN layers ---
    for (int l = 0; l < 3; ++l) {
        const float* xin = (l == 0) ? x : out;
        gemm_mfma<<<(NN + 63) / 64, 256, 0, stream>>>(
            xin, whp + (size_t)l * 16384, wlp + (size_t)l * 16384, dinv, H);
        aggregate<<<NN / 8, 256, 0, stream>>>(H, off, eidx, dinv, b + (size_t)l * DD,
                                              out, (l < 2) ? 1 : 0);
    }
}

// Round 4
// 403.764 us; speedup vs baseline: 1.4423x; 1.0535x over previous
//
#include <hip/hip_runtime.h>
#include <math.h>

#define NN 100000
#define NE 640000
#define DD 128
#define NBLK 391     // ceil(NN/256)
#define LSTRIDE 132  // 128 + 4 pad, keeps rows 16B-aligned

typedef __attribute__((ext_vector_type(8))) short short8;   // 8 bf16 = 4 VGPRs
typedef __attribute__((ext_vector_type(4))) float floatx4;  // MFMA C/D

// ---------------- workspace layout (bytes, 512-aligned) ----------------
static const size_t OFF_DEG    = 0;        // int[NN]
static const size_t OFF_DINV   = 400384;   // float[NN]
static const size_t OFF_OFF    = 800768;   // int[NN+1]
static const size_t OFF_CURSOR = 1201152;  // int[NN]
static const size_t OFF_BSUM   = 1601536;  // int[NBLK]
static const size_t OFF_BBASE  = 1603584;  // int[NBLK]
static const size_t OFF_WHP    = 1605632;  // ushort[3*2048*8]
static const size_t OFF_WLP    = 1703936;  // ushort[3*2048*8]
static const size_t OFF_EIDX   = 1802240;  // int[NE]
static const size_t OFF_H      = 4362752;  // float[NN*DD]

__device__ __forceinline__ unsigned bf16_rne(float f) {
    unsigned u = __float_as_uint(f);
    return (u + 0x7FFFu + ((u >> 16) & 1u)) >> 16;
}

// ---------------- CSR build ----------------

__global__ __launch_bounds__(256) void count_deg(const int* __restrict__ coli,
                                                 int* __restrict__ deg) {
    int e = blockIdx.x * 256 + threadIdx.x;
    if (e < NE) atomicAdd(&deg[coli[e]], 1);
}

__global__ __launch_bounds__(256) void compute_dinv(const int* __restrict__ deg,
                                                    float* __restrict__ dinv) {
    int n = blockIdx.x * 256 + threadIdx.x;
    if (n < NN) {
        int d = deg[n];
        dinv[n] = (d > 0) ? 1.0f / sqrtf((float)d) : 0.0f;
    }
}

__global__ __launch_bounds__(256) void scan_blocks(const int* __restrict__ deg,
                                                   int* __restrict__ loff,
                                                   int* __restrict__ bsum) {
    int tid = threadIdx.x;
    int i = blockIdx.x * 256 + tid;
    int v = (i < NN) ? deg[i] : 0;
    int lane = tid & 63, wid = tid >> 6;
    int sv = v;
    #pragma unroll
    for (int s = 1; s < 64; s <<= 1) {
        int t = __shfl_up(sv, s, 64);
        if (lane >= s) sv += t;
    }
    __shared__ int wtot[4];
    if (lane == 63) wtot[wid] = sv;
    __syncthreads();
    if (tid == 0) {
        int r = 0;
        #pragma unroll
        for (int w = 0; w < 4; ++w) { int t = wtot[w]; wtot[w] = r; r += t; }
    }
    __syncthreads();
    int incl = sv + wtot[wid];
    if (i < NN) loff[i] = incl - v;
    if (tid == 255) bsum[blockIdx.x] = incl;
}

__global__ __launch_bounds__(512) void scan_partials(const int* __restrict__ bsum,
                                                     int* __restrict__ bbase,
                                                     int* __restrict__ off) {
    int tid = threadIdx.x;
    int v = (tid < NBLK) ? bsum[tid] : 0;
    int lane = tid & 63, wid = tid >> 6;
    int sv = v;
    #pragma unroll
    for (int s = 1; s < 64; s <<= 1) {
        int t = __shfl_up(sv, s, 64);
        if (lane >= s) sv += t;
    }
    __shared__ int wtot[8];
    if (lane == 63) wtot[wid] = sv;
    __syncthreads();
    if (tid == 0) {
        int r = 0;
        #pragma unroll
        for (int w = 0; w < 8; ++w) { int t = wtot[w]; wtot[w] = r; r += t; }
    }
    __syncthreads();
    int incl = sv + wtot[wid];
    if (tid < NBLK) bbase[tid] = incl - v;
    if (tid == NBLK - 1) off[NN] = incl;
}

__global__ __launch_bounds__(256) void add_base(int* __restrict__ off,
                                                int* __restrict__ cursor,
                                                const int* __restrict__ bbase) {
    int i = blockIdx.x * 256 + threadIdx.x;
    if (i < NN) {
        int v = off[i] + bbase[blockIdx.x];
        off[i] = v;
        cursor[i] = v;
    }
}

__global__ __launch_bounds__(256) void fill_csr(const int* __restrict__ rowi,
                                                const int* __restrict__ coli,
                                                int* __restrict__ cursor,
                                                int* __restrict__ eidx) {
    int e = blockIdx.x * 256 + threadIdx.x;
    if (e < NE) {
        int s = rowi[e], d = coli[e];
        int pos = atomicAdd(&cursor[d], 1);
        eidx[pos] = s;
    }
}

// ---------------- W pre-split into MFMA B-fragment order ----------------
// Fragment (kc, nt): lane holds B[k][n], n = nt*16 + (lane&15),
// k = kc*32 + (lane>>4)*8 + j, j=0..7 contiguous -> one 16B load per frag.
__global__ __launch_bounds__(256) void pack_w(const float* __restrict__ W,
                                              ushort* __restrict__ Whp,
                                              ushort* __restrict__ Wlp) {
    int t = blockIdx.x * 256 + threadIdx.x;
    if (t >= 3 * 2048) return;
    int l = t >> 11;
    int r = t & 2047;
    int kc = r >> 9;
    int nt = (r >> 6) & 7;
    int L  = r & 63;
    int n  = nt * 16 + (L & 15);
    int k0 = kc * 32 + (L >> 4) * 8;
    const float* Wl_ = W + (size_t)l * DD * DD;
    size_t base = ((size_t)l * 2048 + r) * 8;
    #pragma unroll
    for (int j = 0; j < 8; ++j) {
        float f = Wl_[(size_t)(k0 + j) * DD + n];
        unsigned hi = bf16_rne(f);
        float fh = __uint_as_float(hi << 16);
        unsigned lo = bf16_rne(f - fh);
        Whp[base + j] = (ushort)hi;
        Wlp[base + j] = (ushort)lo;
    }
}

// ---------------- fused layer: Y = relu?( dinv*(A_gather(Xin)) @ W + b ) ----
// Uses A(XW) == (AX)W. Phase 1: 8x32-lane groups aggregate 64 dst rows of
// dinv[src]*Xin[src] into LDS (unroll-4, 4 outstanding gathers/group).
// Phase 2: 4 waves, split-bf16 MFMA vs pre-packed W frags, fused epilogue.
__global__ __launch_bounds__(256, 4) void fused_layer(
        const float* __restrict__ Xin,
        const ushort* __restrict__ Whp,
        const ushort* __restrict__ Wlp,
        const int* __restrict__ off,
        const int* __restrict__ eidx,
        const float* __restrict__ dinv,
        const float* __restrict__ bias,
        float* __restrict__ Y,
        int do_relu) {
    __shared__ float Ls[64 * LSTRIDE];
    int tid = threadIdx.x;
    int n0 = blockIdx.x * 64;

    // ---- phase 1: gather-aggregate into LDS ----
    {
        int g = tid >> 5, lane = tid & 31;
        int c0 = lane * 4;
        for (int t = 0; t < 8; ++t) {
            int nl = g * 8 + t;
            int node = n0 + nl;
            float4 a0 = make_float4(0.f, 0.f, 0.f, 0.f);
            float4 a1 = a0, a2 = a0, a3 = a0;
            if (node < NN) {
                int s = off[node];
                int e = off[node + 1];
                for (int j = s; j < e; j += 4) {
                    int j1 = j + 1, j2 = j + 2, j3 = j + 3;
                    int i1 = (j1 < e) ? j1 : j;
                    int i2 = (j2 < e) ? j2 : j;
                    int i3 = (j3 < e) ? j3 : j;
                    int s0 = eidx[j],  s1 = eidx[i1];
                    int s2 = eidx[i2], s3 = eidx[i3];
                    float w0 = dinv[s0];
                    float w1 = (j1 < e) ? dinv[s1] : 0.f;
                    float w2 = (j2 < e) ? dinv[s2] : 0.f;
                    float w3 = (j3 < e) ? dinv[s3] : 0.f;
                    float4 v0 = *(const float4*)(Xin + (size_t)s0 * DD + c0);
                    float4 v1 = *(const float4*)(Xin + (size_t)s1 * DD + c0);
                    float4 v2 = *(const float4*)(Xin + (size_t)s2 * DD + c0);
                    float4 v3 = *(const float4*)(Xin + (size_t)s3 * DD + c0);
                    a0.x = fmaf(w0, v0.x, a0.x); a0.y = fmaf(w0, v0.y, a0.y);
                    a0.z = fmaf(w0, v0.z, a0.z); a0.w = fmaf(w0, v0.w, a0.w);
                    a1.x = fmaf(w1, v1.x, a1.x); a1.y = fmaf(w1, v1.y, a1.y);
                    a1.z = fmaf(w1, v1.z, a1.z); a1.w = fmaf(w1, v1.w, a1.w);
                    a2.x = fmaf(w2, v2.x, a2.x); a2.y = fmaf(w2, v2.y, a2.y);
                    a2.z = fmaf(w2, v2.z, a2.z); a2.w = fmaf(w2, v2.w, a2.w);
                    a3.x = fmaf(w3, v3.x, a3.x); a3.y = fmaf(w3, v3.y, a3.y);
                    a3.z = fmaf(w3, v3.z, a3.z); a3.w = fmaf(w3, v3.w, a3.w);
                }
            }
            float4 r = make_float4((a0.x + a1.x) + (a2.x + a3.x),
                                   (a0.y + a1.y) + (a2.y + a3.y),
                                   (a0.z + a1.z) + (a2.z + a3.z),
                                   (a0.w + a1.w) + (a2.w + a3.w));
            *(float4*)(&Ls[nl * LSTRIDE + c0]) = r;
        }
    }
    __syncthreads();

    // ---- phase 2: split-bf16 MFMA on aggregated rows ----
    int wave = tid >> 6;
    int lane = tid & 63;
    int m    = lane & 15;
    int quad = lane >> 4;
    int r0   = n0 + wave * 16;

    floatx4 acc[8];
    #pragma unroll
    for (int nt = 0; nt < 8; ++nt) acc[nt] = (floatx4){0.f, 0.f, 0.f, 0.f};

    #pragma unroll
    for (int kc = 0; kc < 4; ++kc) {
        const float* lp = &Ls[(wave * 16 + m) * LSTRIDE + kc * 32 + quad * 8];
        float4 xa = *(const float4*)(lp);
        float4 xb = *(const float4*)(lp + 4);
        float xs[8] = {xa.x, xa.y, xa.z, xa.w, xb.x, xb.y, xb.z, xb.w};
        short8 ah, al;
        #pragma unroll
        for (int j = 0; j < 8; ++j) {
            unsigned hi = bf16_rne(xs[j]);
            float fh = __uint_as_float(hi << 16);
            unsigned lo = bf16_rne(xs[j] - fh);
            ah[j] = (short)hi;
            al[j] = (short)lo;
        }
        #pragma unroll
        for (int nt = 0; nt < 8; ++nt) {
            size_t fidx = (((size_t)(kc * 8 + nt)) * 64 + lane) * 8;
            short8 bh = *(const short8*)(Whp + fidx);
            short8 bl = *(const short8*)(Wlp + fidx);
            acc[nt] = __builtin_amdgcn_mfma_f32_16x16x32_bf16(al, bh, acc[nt], 0, 0, 0);
            acc[nt] = __builtin_amdgcn_mfma_f32_16x16x32_bf16(ah, bl, acc[nt], 0, 0, 0);
            acc[nt] = __builtin_amdgcn_mfma_f32_16x16x32_bf16(ah, bh, acc[nt], 0, 0, 0);
        }
    }

    // C/D: col = nt*16 + m, row = r0 + quad*4 + i
    #pragma unroll
    for (int i = 0; i < 4; ++i) {
        int ro = r0 + quad * 4 + i;
        if (ro < NN) {
            float s = dinv[ro];
            float* yp = Y + (size_t)ro * DD + m;
            #pragma unroll
            for (int nt = 0; nt < 8; ++nt) {
                float v = acc[nt][i] * s + bias[nt * 16 + m];
                if (do_relu) v = fmaxf(v, 0.f);
                yp[nt * 16] = v;
            }
        }
    }
}

// ---------------- launch ----------------

extern "C" void kernel_launch(void* const* d_in, const int* in_sizes, int n_in,
                              void* d_out, int out_size, void* d_ws, size_t ws_size,
                              hipStream_t stream) {
    const float* x  = (const float*)d_in[0];
    const int*   ei = (const int*)d_in[1];   // [2, NE] flattened, int32
    const float* W  = (const float*)d_in[3]; // [3, DD, DD]
    const float* b  = (const float*)d_in[4]; // [3, DD]
    float* out = (float*)d_out;

    char* ws = (char*)d_ws;
    int*    deg    = (int*)(ws + OFF_DEG);
    float*  dinv   = (float*)(ws + OFF_DINV);
    int*    off    = (int*)(ws + OFF_OFF);
    int*    cursor = (int*)(ws + OFF_CURSOR);
    int*    bsum   = (int*)(ws + OFF_BSUM);
    int*    bbase  = (int*)(ws + OFF_BBASE);
    ushort* whp    = (ushort*)(ws + OFF_WHP);
    ushort* wlp    = (ushort*)(ws + OFF_WLP);
    int*    eidx   = (int*)(ws + OFF_EIDX);
    float*  H      = (float*)(ws + OFF_H);

    const int* rowi = ei;        // sources
    const int* coli = ei + NE;   // targets

    // --- CSR build + W pre-split (once per call) ---
    hipMemsetAsync(deg, 0, NN * sizeof(int), stream);
    count_deg<<<(NE + 255) / 256, 256, 0, stream>>>(coli, deg);
    compute_dinv<<<(NN + 255) / 256, 256, 0, stream>>>(deg, dinv);
    scan_blocks<<<NBLK, 256, 0, stream>>>(deg, off, bsum);
    scan_partials<<<1, 512, 0, stream>>>(bsum, bbase, off);
    add_base<<<NBLK, 256, 0, stream>>>(off, cursor, bbase);
    fill_csr<<<(NE + 255) / 256, 256, 0, stream>>>(rowi, coli, cursor, eidx);
    pack_w<<<(3 * 2048 + 255) / 256, 256, 0, stream>>>(W, whp, wlp);

    // --- 3 fused layers; buffer chain x -> out -> H -> out (no RW races) ---
    int nblk = (NN + 63) / 64;
    fused_layer<<<nblk, 256, 0, stream>>>(x,   whp,         wlp,         off, eidx,
                                          dinv, b,          out, 1);
    fused_layer<<<nblk, 256, 0, stream>>>(out, whp + 16384, wlp + 16384, off, eidx,
                                          dinv, b + DD,     H,   1);
    fused_layer<<<nblk, 256, 0, stream>>>(H,   whp + 32768, wlp + 32768, off, eidx,
                                          dinv, b + 2 * DD, out, 0);
}

// Round 5
// 371.936 us; speedup vs baseline: 1.5657x; 1.0856x over previous
//
#include <hip/hip_runtime.h>
#include <math.h>

#define NN 100000
#define NE 640000
#define DD 128
#define NBLK 391     // ceil(NN/256)
#define LSTRIDE 132  // 128 + 4 pad, keeps rows 16B-aligned, breaks pow2 stride

typedef __attribute__((ext_vector_type(8))) short short8;   // 8 bf16 = 4 VGPRs
typedef __attribute__((ext_vector_type(4))) float floatx4;  // MFMA C/D

// ---------------- workspace layout (bytes) ----------------
// [0, 403456) zeroed by one memsetAsync: deg + scan state + ticket
static const size_t OFF_DEG    = 0;        // int[NN]             (400000)
static const size_t OFF_STATE  = 400000;   // u64[NBLK]           (3128)
static const size_t OFF_TICKET = 403128;   // uint                (4)
static const size_t OFF_DINV   = 403456;   // float[NN]
static const size_t OFF_OFF    = 803456;   // int[NN+1]
static const size_t OFF_CURSOR = 1203712;  // int[NN]
static const size_t OFF_WHP    = 1604096;  // ushort[3*2048*8]
static const size_t OFF_WLP    = 1702400;  // ushort[3*2048*8]
static const size_t OFF_EIDX   = 1800704;  // int[NE]
static const size_t OFF_H      = 4360704;  // float[NN*DD]

#define FLAG_A (1ULL << 62)
#define FLAG_P (2ULL << 62)

__device__ __forceinline__ unsigned bf16_rne(float f) {
    unsigned u = __float_as_uint(f);
    return (u + 0x7FFFu + ((u >> 16) & 1u)) >> 16;
}

// ---------------- setup: degree count + W pre-split (merged) ----------------
// Fragment (kc, nt): lane holds B[k][n], n = nt*16 + (lane&15),
// k = kc*32 + (lane>>4)*8 + j, j contiguous -> one 16B load per frag.
__global__ __launch_bounds__(256) void count_and_pack(const int* __restrict__ coli,
                                                      int* __restrict__ deg,
                                                      const float* __restrict__ W,
                                                      ushort* __restrict__ Whp,
                                                      ushort* __restrict__ Wlp) {
    int e = blockIdx.x * 256 + threadIdx.x;
    if (e < NE) atomicAdd(&deg[coli[e]], 1);
    if (e < 3 * 2048) {
        int l = e >> 11;
        int r = e & 2047;
        int kc = r >> 9;
        int nt = (r >> 6) & 7;
        int L  = r & 63;
        int n  = nt * 16 + (L & 15);
        int k0 = kc * 32 + (L >> 4) * 8;
        const float* Wl_ = W + (size_t)l * DD * DD;
        size_t base = ((size_t)l * 2048 + r) * 8;
        #pragma unroll
        for (int j = 0; j < 8; ++j) {
            float f = Wl_[(size_t)(k0 + j) * DD + n];
            unsigned hi = bf16_rne(f);
            float fh = __uint_as_float(hi << 16);
            unsigned lo = bf16_rne(f - fh);
            Whp[base + j] = (ushort)hi;
            Wlp[base + j] = (ushort)lo;
        }
    }
}

// ---------------- setup: single-pass scan (decoupled lookback) + dinv ------
// Ticket-ordered virtual block ids guarantee all lower tickets are running.
__global__ __launch_bounds__(256) void scan_fused(const int* __restrict__ deg,
                                                  int* __restrict__ off,
                                                  int* __restrict__ cursor,
                                                  float* __restrict__ dinv,
                                                  unsigned long long* __restrict__ state,
                                                  unsigned* __restrict__ ticket) {
    __shared__ int sbid;
    int tid = threadIdx.x;
    if (tid == 0) sbid = (int)atomicAdd(ticket, 1u);
    __syncthreads();
    int bid = sbid;
    int i = bid * 256 + tid;
    int v = (i < NN) ? deg[i] : 0;
    if (i < NN) dinv[i] = (v > 0) ? 1.0f / sqrtf((float)v) : 0.0f;

    int lane = tid & 63, wid = tid >> 6;
    int sv = v;
    #pragma unroll
    for (int s = 1; s < 64; s <<= 1) {
        int t = __shfl_up(sv, s, 64);
        if (lane >= s) sv += t;
    }
    __shared__ int wtot[4];
    __shared__ int prevsum;
    if (lane == 63) wtot[wid] = sv;
    __syncthreads();
    if (tid == 0) {
        int r = 0;
        #pragma unroll
        for (int w = 0; w < 4; ++w) { int t = wtot[w]; wtot[w] = r; r += t; }
        // publish block aggregate, then look back
        atomicExch(&state[bid], FLAG_A | (unsigned long long)(unsigned)r);
        unsigned long long run = 0;
        for (int j = bid - 1; j >= 0; ) {
            unsigned long long s = atomicAdd(&state[j], 0ULL);  // coherent read
            if (s & FLAG_P)      { run += (unsigned)s; break; }
            else if (s & FLAG_A) { run += (unsigned)s; --j; }
            // else: predecessor hasn't published yet -> spin on same j
        }
        atomicExch(&state[bid], FLAG_P | (unsigned long long)(unsigned)(run + (unsigned)r));
        prevsum = (int)run;
        if (bid == NBLK - 1) off[NN] = (int)(run + (unsigned)r);
    }
    __syncthreads();
    int incl = sv + wtot[wid] + prevsum;
    if (i < NN) {
        int o = incl - v;
        off[i] = o;
        cursor[i] = o;
    }
}

__global__ __launch_bounds__(256) void fill_csr(const int* __restrict__ rowi,
                                                const int* __restrict__ coli,
                                                int* __restrict__ cursor,
                                                int* __restrict__ eidx) {
    int e = blockIdx.x * 256 + threadIdx.x;
    if (e < NE) {
        int s = rowi[e], d = coli[e];
        int pos = atomicAdd(&cursor[d], 1);
        eidx[pos] = s;
    }
}

// ---------------- fused layer: Y = relu?( dinv*(A_gather(Xin)) @ W + b ) ----
// A(XW) == (AX)W. 32 dst nodes / 256-thread block, LDS 16.9 KB -> 8 blocks/CU.
// Phase 1: 8 groups x 4 nodes, unroll-4 (4 outstanding 16B gathers per lane).
// Phase 2: 2x8 grid of 16x16 MFMA tiles split 4-per-wave across 4 waves.
__global__ __launch_bounds__(256) void fused_layer(
        const float* __restrict__ Xin,
        const ushort* __restrict__ Whp,
        const ushort* __restrict__ Wlp,
        const int* __restrict__ off,
        const int* __restrict__ eidx,
        const float* __restrict__ dinv,
        const float* __restrict__ bias,
        float* __restrict__ Y,
        int do_relu) {
    __shared__ float Ls[32 * LSTRIDE];
    int tid = threadIdx.x;
    int n0 = blockIdx.x * 32;

    // ---- phase 1: gather-aggregate 32 rows of dinv[src]*Xin[src] into LDS ----
    {
        int g = tid >> 5, lane = tid & 31;
        int c0 = lane * 4;
        #pragma unroll
        for (int t = 0; t < 4; ++t) {
            int nl = g * 4 + t;
            int node = n0 + nl;
            float4 a0 = make_float4(0.f, 0.f, 0.f, 0.f);
            float4 a1 = a0, a2 = a0, a3 = a0;
            if (node < NN) {
                int s = off[node];
                int e = off[node + 1];
                for (int j = s; j < e; j += 4) {
                    int j1 = j + 1, j2 = j + 2, j3 = j + 3;
                    int i1 = (j1 < e) ? j1 : j;
                    int i2 = (j2 < e) ? j2 : j;
                    int i3 = (j3 < e) ? j3 : j;
                    int s0 = eidx[j],  s1 = eidx[i1];
                    int s2 = eidx[i2], s3 = eidx[i3];
                    float w0 = dinv[s0];
                    float w1 = (j1 < e) ? dinv[s1] : 0.f;
                    float w2 = (j2 < e) ? dinv[s2] : 0.f;
                    float w3 = (j3 < e) ? dinv[s3] : 0.f;
                    float4 v0 = *(const float4*)(Xin + (size_t)s0 * DD + c0);
                    float4 v1 = *(const float4*)(Xin + (size_t)s1 * DD + c0);
                    float4 v2 = *(const float4*)(Xin + (size_t)s2 * DD + c0);
                    float4 v3 = *(const float4*)(Xin + (size_t)s3 * DD + c0);
                    a0.x = fmaf(w0, v0.x, a0.x); a0.y = fmaf(w0, v0.y, a0.y);
                    a0.z = fmaf(w0, v0.z, a0.z); a0.w = fmaf(w0, v0.w, a0.w);
                    a1.x = fmaf(w1, v1.x, a1.x); a1.y = fmaf(w1, v1.y, a1.y);
                    a1.z = fmaf(w1, v1.z, a1.z); a1.w = fmaf(w1, v1.w, a1.w);
                    a2.x = fmaf(w2, v2.x, a2.x); a2.y = fmaf(w2, v2.y, a2.y);
                    a2.z = fmaf(w2, v2.z, a2.z); a2.w = fmaf(w2, v2.w, a2.w);
                    a3.x = fmaf(w3, v3.x, a3.x); a3.y = fmaf(w3, v3.y, a3.y);
                    a3.z = fmaf(w3, v3.z, a3.z); a3.w = fmaf(w3, v3.w, a3.w);
                }
            }
            float4 r = make_float4((a0.x + a1.x) + (a2.x + a3.x),
                                   (a0.y + a1.y) + (a2.y + a3.y),
                                   (a0.z + a1.z) + (a2.z + a3.z),
                                   (a0.w + a1.w) + (a2.w + a3.w));
            *(float4*)(&Ls[nl * LSTRIDE + c0]) = r;
        }
    }
    __syncthreads();

    // ---- phase 2: split-bf16 MFMA; wave w: row tile mt=w>>1, col tiles nh..nh+3 ----
    int wave = tid >> 6;
    int lane = tid & 63;
    int m    = lane & 15;
    int quad = lane >> 4;
    int mt   = wave >> 1;
    int nh   = (wave & 1) * 4;

    floatx4 acc[4];
    #pragma unroll
    for (int q = 0; q < 4; ++q) acc[q] = (floatx4){0.f, 0.f, 0.f, 0.f};

    #pragma unroll
    for (int kc = 0; kc < 4; ++kc) {
        const float* lp = &Ls[(mt * 16 + m) * LSTRIDE + kc * 32 + quad * 8];
        float4 xa = *(const float4*)(lp);
        float4 xb = *(const float4*)(lp + 4);
        float xs[8] = {xa.x, xa.y, xa.z, xa.w, xb.x, xb.y, xb.z, xb.w};
        short8 ah, al;
        #pragma unroll
        for (int j = 0; j < 8; ++j) {
            unsigned hi = bf16_rne(xs[j]);
            float fh = __uint_as_float(hi << 16);
            unsigned lo = bf16_rne(xs[j] - fh);
            ah[j] = (short)hi;
            al[j] = (short)lo;
        }
        #pragma unroll
        for (int q = 0; q < 4; ++q) {
            int nt = nh + q;
            size_t fidx = (((size_t)(kc * 8 + nt)) * 64 + lane) * 8;
            short8 bh = *(const short8*)(Whp + fidx);
            short8 bl = *(const short8*)(Wlp + fidx);
            acc[q] = __builtin_amdgcn_mfma_f32_16x16x32_bf16(al, bh, acc[q], 0, 0, 0);
            acc[q] = __builtin_amdgcn_mfma_f32_16x16x32_bf16(ah, bl, acc[q], 0, 0, 0);
            acc[q] = __builtin_amdgcn_mfma_f32_16x16x32_bf16(ah, bh, acc[q], 0, 0, 0);
        }
    }

    // C/D: col = nt*16 + m, row = n0 + mt*16 + quad*4 + i
    #pragma unroll
    for (int i = 0; i < 4; ++i) {
        int ro = n0 + mt * 16 + quad * 4 + i;
        if (ro < NN) {
            float s = dinv[ro];
            #pragma unroll
            for (int q = 0; q < 4; ++q) {
                int col = (nh + q) * 16 + m;
                float v = acc[q][i] * s + bias[col];
                if (do_relu) v = fmaxf(v, 0.f);
                Y[(size_t)ro * DD + col] = v;
            }
        }
    }
}

// ---------------- launch ----------------

extern "C" void kernel_launch(void* const* d_in, const int* in_sizes, int n_in,
                              void* d_out, int out_size, void* d_ws, size_t ws_size,
                              hipStream_t stream) {
    const float* x  = (const float*)d_in[0];
    const int*   ei = (const int*)d_in[1];   // [2, NE] flattened, int32
    const float* W  = (const float*)d_in[3]; // [3, DD, DD]
    const float* b  = (const float*)d_in[4]; // [3, DD]
    float* out = (float*)d_out;

    char* ws = (char*)d_ws;
    int*    deg    = (int*)(ws + OFF_DEG);
    unsigned long long* state = (unsigned long long*)(ws + OFF_STATE);
    unsigned* ticket = (unsigned*)(ws + OFF_TICKET);
    float*  dinv   = (float*)(ws + OFF_DINV);
    int*    off    = (int*)(ws + OFF_OFF);
    int*    cursor = (int*)(ws + OFF_CURSOR);
    ushort* whp    = (ushort*)(ws + OFF_WHP);
    ushort* wlp    = (ushort*)(ws + OFF_WLP);
    int*    eidx   = (int*)(ws + OFF_EIDX);
    float*  H      = (float*)(ws + OFF_H);

    const int* rowi = ei;        // sources
    const int* coli = ei + NE;   // targets

    // --- setup: 4 dispatches ---
    hipMemsetAsync(ws, 0, 403456, stream);  // deg + state + ticket
    count_and_pack<<<(NE + 255) / 256, 256, 0, stream>>>(coli, deg, W, whp, wlp);
    scan_fused<<<NBLK, 256, 0, stream>>>(deg, off, cursor, dinv, state, ticket);
    fill_csr<<<(NE + 255) / 256, 256, 0, stream>>>(rowi, coli, cursor, eidx);

    // --- 3 fused layers; buffer chain x -> out -> H -> out (no RW races) ---
    int nblk = (NN + 31) / 32;
    fused_layer<<<nblk, 256, 0, stream>>>(x,   whp,         wlp,         off, eidx,
                                          dinv, b,          out, 1);
    fused_layer<<<nblk, 256, 0, stream>>>(out, whp + 16384, wlp + 16384, off, eidx,
                                          dinv, b + DD,     H,   1);
    fused_layer<<<nblk, 256, 0, stream>>>(H,   whp + 32768, wlp + 32768, off, eidx,
                                          dinv, b + 2 * DD, out, 0);
}